// Round 9
// baseline (247.589 us; speedup 1.0000x reference)
//
#include <hip/hip_runtime.h>
#include <hip/hip_bf16.h>

#define D_DIM 256
#define K_CODES 1024
#define HW 1024
#define N_VEC 32768
#define N_ELEM 8388608ull

typedef __attribute__((ext_vector_type(8))) short bf16x8;
typedef __attribute__((ext_vector_type(4))) float f32x4;

static __device__ __forceinline__ unsigned short f2bf(float x) {
    union { __hip_bfloat16 h; unsigned short u; } cvt;
    cvt.h = __float2bfloat16(x);
    return cvt.u;
}

// ---------------------------------------------------------------------------
// Kernel A (fused prep): codebook -> bf16 B-fragment order + codebook norms
// + zero counts/lossacc. 128 blocks x 256.
// ---------------------------------------------------------------------------
__global__ __launch_bounds__(256) void prep_kernel(const float* __restrict__ cb,
                                                   unsigned short* __restrict__ cbb,
                                                   float* __restrict__ cnorm,
                                                   int* __restrict__ counts,
                                                   float* __restrict__ lossacc) {
    int slot = blockIdx.x * 256 + threadIdx.x;  // 0 .. 32767
    {
        int lane = slot & 63;
        int dchunk = (slot >> 6) & 7;
        int ktile = slot >> 9;
        int code = ktile * 16 + (lane & 15);
        int d0 = dchunk * 32 + (lane >> 4) * 8;
        const float4* src = (const float4*)(cb + (size_t)code * D_DIM + d0);
        float4 v0 = src[0], v1 = src[1];
        int4 o;
        o.x = f2bf(v0.x) | ((unsigned)f2bf(v0.y) << 16);
        o.y = f2bf(v0.z) | ((unsigned)f2bf(v0.w) << 16);
        o.z = f2bf(v1.x) | ((unsigned)f2bf(v1.y) << 16);
        o.w = f2bf(v1.z) | ((unsigned)f2bf(v1.w) << 16);
        *(int4*)(cbb + (size_t)slot * 8) = o;
    }
    if (slot < 8192) {
        if (slot < K_CODES) counts[slot] = 0;
        if (slot == K_CODES) lossacc[0] = 0.f;
        int k = slot >> 3;
        int part = slot & 7;
        const float4* row = (const float4*)(cb + (size_t)k * D_DIM + part * 32);
        float s = 0.f;
#pragma unroll
        for (int i = 0; i < 8; i++) {
            float4 v = row[i];
            s = fmaf(v.x, v.x, s);
            s = fmaf(v.y, v.y, s);
            s = fmaf(v.z, v.z, s);
            s = fmaf(v.w, v.w, s);
        }
        s += __shfl_xor(s, 1);
        s += __shfl_xor(s, 2);
        s += __shfl_xor(s, 4);
        if (part == 0) cnorm[k] = s;
    }
}

// ---------------------------------------------------------------------------
// Kernel B: argmin via bf16 MFMA (R8 structure) + FUSED LOSS.
// Block = 512 thr (8 waves) = 128 n, in-block split-K (waves 0-3: codes
// [0,512), waves 4-7: [512,1024)). B staged via global_load_lds(16B) dbuf.
// Loss: ||q-z||^2 = bestd + ||z||^2; ||z||^2 accumulated in fp32 during the
// A-fragment prologue, combined at the final reduce, one atomicAdd per block.
// ---------------------------------------------------------------------------
__global__ __launch_bounds__(512, 2) void argmin_mfma(const float* __restrict__ z,
                                                      const unsigned short* __restrict__ cbb,
                                                      const float* __restrict__ cnorm,
                                                      int* __restrict__ indices,
                                                      int* __restrict__ counts,
                                                      float* __restrict__ lossacc) {
    __shared__ __align__(16) unsigned short Bbuf[2][2][8192];  // [dbuf][half][16KB]
    __shared__ float sd[128][2];
    __shared__ int sk[128][2];
    __shared__ float znL[128];
    __shared__ float wsumL[2];
    const int t = threadIdx.x;
    const int lane = t & 63;
    const int w = t >> 6;   // wave 0..7
    const int p = w & 3;    // ntile pair within block
    const int h = w >> 2;   // K-half
    const int nt0 = blockIdx.x * 8 + p * 2;

    const int seg = t >> 8;  // staging role: which half's buffer
    const int tt = t & 255;

    // ---- prologue: load + convert A fragments; accumulate ||z||^2 (fp32) ----
    bf16x8 Ar[2][8];
    {
        const int row = lane & 15;
        const int dq = (lane >> 4) * 8;
#pragma unroll
        for (int nt = 0; nt < 2; nt++) {
            int n = (nt0 + nt) * 16 + row;
            int b = n >> 10;
            int hw = n & (HW - 1);
            float zsq = 0.f;
#pragma unroll
            for (int dc = 0; dc < 8; dc++) {
                const float* src = z + (((size_t)(b * D_DIM + dc * 32 + dq)) << 10) + hw;
                union { bf16x8 v; unsigned short u[8]; } pk;
#pragma unroll
                for (int j = 0; j < 8; j++) {
                    float v = src[(size_t)j << 10];
                    zsq = fmaf(v, v, zsq);
                    pk.u[j] = f2bf(v);
                }
                Ar[nt][dc] = pk.v;
            }
            // 4 lanes (row, row+16, row+32, row+48) hold d-quarters of this n
            zsq += __shfl_xor(zsq, 16);
            zsq += __shfl_xor(zsq, 32);
            if (w < 4 && lane < 16) znL[(p * 2 + nt) * 16 + lane] = zsq;
        }
    }

    // ---- async stage of iteration 0 ----
    {
        const unsigned int* g = (const unsigned int*)(cbb + (size_t)seg * 32 * 4096);
        unsigned int* l = (unsigned int*)&Bbuf[0][seg][0];
#pragma unroll
        for (int pp = 0; pp < 4; pp++) {
            int off = (pp * 256 + tt) * 4;
            __builtin_amdgcn_global_load_lds(
                (const __attribute__((address_space(1))) unsigned int*)(g + off),
                (__attribute__((address_space(3))) unsigned int*)(l + off), 16, 0, 0);
        }
    }

    float bestd[2][4];
    int bestk[2][4];
#pragma unroll
    for (int nt = 0; nt < 2; nt++)
#pragma unroll
        for (int r = 0; r < 4; r++) { bestd[nt][r] = 3.4e38f; bestk[nt][r] = 0; }

    const int col = lane & 15;
    for (int c = 0; c < 16; c++) {
        const int cur = c & 1;
        __syncthreads();  // drains vmcnt -> Bbuf[cur] ready for all waves
        if (c < 15) {
            const unsigned int* g = (const unsigned int*)
                (cbb + ((size_t)seg * 32 + (size_t)(c + 1) * 2) * 4096);
            unsigned int* l = (unsigned int*)&Bbuf[cur ^ 1][seg][0];
#pragma unroll
            for (int pp = 0; pp < 4; pp++) {
                int off = (pp * 256 + tt) * 4;
                __builtin_amdgcn_global_load_lds(
                    (const __attribute__((address_space(1))) unsigned int*)(g + off),
                    (__attribute__((address_space(3))) unsigned int*)(l + off), 16, 0, 0);
            }
        }
        const unsigned short* Bb = &Bbuf[cur][h][0];
        bf16x8 bb[2][8];
#pragma unroll
        for (int kt2 = 0; kt2 < 2; kt2++)
#pragma unroll
            for (int dc = 0; dc < 8; dc++)
                bb[kt2][dc] = *(const bf16x8*)&Bb[((kt2 * 8 + dc) * 64 + lane) * 8];
        f32x4 acc[2][2];
#pragma unroll
        for (int nt = 0; nt < 2; nt++)
#pragma unroll
            for (int kt2 = 0; kt2 < 2; kt2++)
                acc[nt][kt2] = (f32x4){0.f, 0.f, 0.f, 0.f};
#pragma unroll
        for (int dc = 0; dc < 8; dc++)
#pragma unroll
            for (int nt = 0; nt < 2; nt++)
#pragma unroll
                for (int kt2 = 0; kt2 < 2; kt2++)
                    acc[nt][kt2] = __builtin_amdgcn_mfma_f32_16x16x32_bf16(
                        Ar[nt][dc], bb[kt2][dc], acc[nt][kt2], 0, 0, 0);
#pragma unroll
        for (int kt2 = 0; kt2 < 2; kt2++) {
            int k = (h * 32 + c * 2 + kt2) * 16 + col;
            float cn = cnorm[k];
#pragma unroll
            for (int nt = 0; nt < 2; nt++)
#pragma unroll
                for (int r = 0; r < 4; r++) {
                    float sc = fmaf(-2.0f, acc[nt][kt2][r], cn);
                    if (sc < bestd[nt][r]) { bestd[nt][r] = sc; bestk[nt][r] = k; }
                }
        }
    }

    // ---- reduce across 16 columns; stash per-half result in LDS ----
#pragma unroll
    for (int nt = 0; nt < 2; nt++)
#pragma unroll
        for (int r = 0; r < 4; r++) {
            float dd = bestd[nt][r];
            int kk = bestk[nt][r];
#pragma unroll
            for (int off = 8; off >= 1; off >>= 1) {
                float d2 = __shfl_xor(dd, off);
                int k2 = __shfl_xor(kk, off);
                if (d2 < dd || (d2 == dd && k2 < kk)) { dd = d2; kk = k2; }
            }
            if ((lane & 15) == 0) {
                int nloc = (p * 2 + nt) * 16 + (lane >> 4) * 4 + r;
                sd[nloc][h] = dd;
                sk[nloc][h] = kk;
            }
        }
    __syncthreads();
    if (t < 128) {  // waves 0 and 1, wave-uniform branch
        float d0 = sd[t][0], d1 = sd[t][1];
        int k0 = sk[t][0], k1 = sk[t][1];
        int kk = (d1 < d0) ? k1 : k0;  // half-0 has smaller k: strict <
        indices[blockIdx.x * 128 + t] = kk;
        atomicAdd(&counts[kk], 1);
        float lossn = fminf(d0, d1) + znL[t];  // ||q - z||^2 for this n
#pragma unroll
        for (int off = 32; off >= 1; off >>= 1) lossn += __shfl_down(lossn, off);
        if (lane == 0) wsumL[w] = lossn;
    }
    __syncthreads();
    if (t == 0) atomicAdd(lossacc, wsumL[0] + wsumL[1]);
}

// ---------------------------------------------------------------------------
// Kernel C: fused scatter_store — quantized output (= q exactly; ref's
// z+(q-z) is q within 1 ulp) + one-hot encodings. No z read at all.
// Block = 32 n (one b, 32 hw); stage 32 codebook rows in LDS (stride 257),
// write q in NCHW order (coalesced) then the 32 enc rows (float2 stores,
// enc base is 8B-aligned).
// ---------------------------------------------------------------------------
__global__ __launch_bounds__(256) void scatter_store(const float* __restrict__ cb,
                                                     const int* __restrict__ indices,
                                                     float* __restrict__ outq,
                                                     float* __restrict__ enc) {
    __shared__ float qs[32 * 257];
    __shared__ int skl[32];
    const int t = threadIdx.x;
    const int lane = t & 63;
    const int w = t >> 6;
    const int n0 = blockIdx.x * 32;
    const int b = n0 >> 10;
    const int hw0 = n0 & (HW - 1);

    {  // stage rows (R5-proven pattern) + indices to LDS
        const int rsub = lane >> 4;  // 0..3
        const int f4b = lane & 15;   // 0..15
#pragma unroll
        for (int j = 0; j < 2; j++) {
            int r = (w * 2 + j) * 4 + rsub;  // 0..31
            int code = indices[n0 + r];
            const float4* src = (const float4*)(cb + (size_t)code * D_DIM);
#pragma unroll
            for (int k = 0; k < 4; k++) {
                int f4 = f4b + 16 * k;  // 0..63
                float4 v = src[f4];
                float* dst = &qs[r * 257 + f4 * 4];
                dst[0] = v.x;
                dst[1] = v.y;
                dst[2] = v.z;
                dst[3] = v.w;
            }
        }
        if (t < 32) skl[t] = indices[n0 + t];
    }
    __syncthreads();

    // ---- quantized output: lane -> hw (coalesced), waves split d ----
    const int h = lane & 31;
    const int dhalf = lane >> 5;  // 0 or 1
#pragma unroll 4
    for (int i = 0; i < 32; i++) {
        int d = (i * 4 + w) * 2 + dhalf;  // 0..255
        size_t o = (((size_t)(b * D_DIM + d)) << 10) + hw0 + h;
        outq[o] = qs[h * 257 + d];
    }

    // ---- one-hot encodings for these 32 n (row-uniform idx, coalesced) ----
    const int k0 = t << 2;
#pragma unroll 4
    for (int i = 0; i < 32; i++) {
        int idx = skl[i];
        float2 a, b2;
        a.x = (k0 == idx) ? 1.f : 0.f;
        a.y = (k0 + 1 == idx) ? 1.f : 0.f;
        b2.x = (k0 + 2 == idx) ? 1.f : 0.f;
        b2.y = (k0 + 3 == idx) ? 1.f : 0.f;
        float* ptr = enc + ((size_t)(n0 + i) << 10) + k0;
        *(float2*)ptr = a;
        *(float2*)(ptr + 2) = b2;
    }
}

// ---------------------------------------------------------------------------
// Kernel D: finalize loss + perplexity
// ---------------------------------------------------------------------------
__global__ __launch_bounds__(256) void finalize_kernel(const int* __restrict__ counts,
                                                       const float* __restrict__ lossacc,
                                                       float* __restrict__ out_scalars) {
    int t = threadIdx.x;
    float s = 0.f;
#pragma unroll
    for (int i = 0; i < 4; i++) {
        int k = t + i * 256;
        float p = (float)counts[k] * (1.0f / 32768.0f);
        s += p * logf(p + 1e-10f);
    }
#pragma unroll
    for (int off = 32; off >= 1; off >>= 1) s += __shfl_down(s, off);
    __shared__ float red[4];
    if ((t & 63) == 0) red[t >> 6] = s;
    __syncthreads();
    if (t == 0) {
        float tot = red[0] + red[1] + red[2] + red[3];
        out_scalars[0] = 1.25f * (lossacc[0] * (1.0f / 8388608.0f));  // q + beta*e
        out_scalars[1] = expf(-tot);                                  // perplexity
    }
}

// ---------------------------------------------------------------------------
extern "C" void kernel_launch(void* const* d_in, const int* in_sizes, int n_in,
                              void* d_out, int out_size, void* d_ws, size_t ws_size,
                              hipStream_t stream) {
    const float* z = (const float*)d_in[0];   // [32,256,32,32]
    const float* cb = (const float*)d_in[1];  // [1024,256]
    float* out = (float*)d_out;
    char* wsb = (char*)d_ws;

    float* cnorm = (float*)wsb;             // 1024 f32
    int* counts = (int*)(wsb + 4096);       // 1024 i32
    float* lossacc = (float*)(wsb + 8192);  // 1 f32
    int* indices = (int*)(wsb + 16384);     // 32768 i32

    float* quant = out;             // [0, 8388608)
    float* scal = out + N_ELEM;     // loss @ +0, perplexity @ +1
    float* enc = out + N_ELEM + 2;  // [8388610, +33554432)

    // cbb (512KB, bf16 fragment order) lives inside the encodings region of
    // d_out; fully consumed by argmin_mfma before scatter_store overwrites.
    unsigned short* cbb = (unsigned short*)(out + 8388612);  // 16B-aligned

    hipLaunchKernelGGL(prep_kernel, dim3(128), dim3(256), 0, stream, cb, cbb,
                       cnorm, counts, lossacc);
    hipLaunchKernelGGL(argmin_mfma, dim3(256), dim3(512), 0, stream, z, cbb,
                       cnorm, indices, counts, lossacc);
    hipLaunchKernelGGL(scatter_store, dim3(1024), dim3(256), 0, stream, cb,
                       indices, quant, enc);
    hipLaunchKernelGGL(finalize_kernel, dim3(1), dim3(256), 0, stream, counts,
                       lossacc, scal);
}